// Round 12
// baseline (172.010 us; speedup 1.0000x reference)
//
#include <hip/hip_runtime.h>
#include <hip/hip_bf16.h>

#define CC 728
#define PP 364          // pairs (even/odd phase length)
#define KP 384          // padded pair-K: 12 * 32
#define KT 12
#define M_ROWS 46208    // 32*38*38 = 361 * 128
#define NWG 2166        // 361 m-tiles * 6 n-tiles (64 pairs each)

typedef __attribute__((ext_vector_type(8))) short bf16x8;
typedef __attribute__((ext_vector_type(8))) unsigned short ushort8;
typedef __attribute__((ext_vector_type(4))) float f32x4;

// round-to-nearest-even fp32 -> bf16 bits
__device__ __forceinline__ unsigned int f2bf(float f) {
    unsigned int u = __float_as_uint(f);
    unsigned int r = u + 0x7fffu + ((u >> 16) & 1u);
    return r >> 16;
}

__device__ __forceinline__ float bf2f(unsigned short v) {
    unsigned int u = ((unsigned int)v) << 16;
    return __uint_as_float(u);
}

__device__ __forceinline__ void gload_lds16(const void* g, void* l) {
    __builtin_amdgcn_global_load_lds(
        (const __attribute__((address_space(1))) void*)g,
        (__attribute__((address_space(3))) void*)l,
        16, 0, 0);
}

// h[d] for odd d (validated closed form, rounds 1-11):
//   h[d] = s * cos(pi d/728) / (728 sin(pi d/728)),  s = +1 if (d>>1)&1 else -1
// Bt1[n][k] = h[2*((n-k-1) mod 364)+1]   (Ye = 0.5 E + Bt1 . O)
// Bt2[n][k] = h[2*((n-k)   mod 364)+1]   (Yo = 0.5 O + Bt2 . E)
// Both padded to [384][384] bf16, zero outside n<364 && k<364.
__global__ void build_bt(unsigned short* __restrict__ bt1,
                         unsigned short* __restrict__ bt2) {
    int idx = blockIdx.x * blockDim.x + threadIdx.x;
    if (idx >= 2 * KP * KP) return;
    int mat = idx / (KP * KP);
    int rem = idx % (KP * KP);
    int n = rem / KP, k = rem % KP;
    float v = 0.f;
    if (n < PP && k < PP) {
        int m = n - k - (mat == 0 ? 1 : 0);
        if (m < 0) m += PP;
        int d = 2 * m + 1;
        float t = (float)(3.14159265358979323846 * (double)d / (double)CC);
        float s = ((d >> 1) & 1) ? 1.f : -1.f;
        v = s * cosf(t) / ((float)CC * sinf(t));
    }
    (mat == 0 ? bt1 : bt2)[n * KP + k] = (unsigned short)f2bf(v);
}

// Pass 1: x fp32 [46208][728] -> e,o bf16 [46208][384] (de-interleaved, padded)
__global__ void convert_deint(const float* __restrict__ x,
                              unsigned short* __restrict__ e,
                              unsigned short* __restrict__ o) {
    int id = blockIdx.x * blockDim.x + threadIdx.x;   // r*48 + p8
    if (id >= M_ROWS * 48) return;
    int r  = id / 48, p8 = id % 48;
    int c0 = p8 * 16;
    ushort8 ve, vo;
#pragma unroll
    for (int j = 0; j < 8; ++j) { ve[j] = 0; vo[j] = 0; }
    if (c0 < CC) {
        const float4* src = (const float4*)(x + (size_t)r * CC + c0);
#pragma unroll
        for (int j = 0; j < 4; ++j) {
            float4 f = (c0 + 4 * j < CC) ? src[j] : make_float4(0.f, 0.f, 0.f, 0.f);
            ve[2 * j]     = (unsigned short)f2bf(f.x);
            vo[2 * j]     = (unsigned short)f2bf(f.y);
            ve[2 * j + 1] = (unsigned short)f2bf(f.z);
            vo[2 * j + 1] = (unsigned short)f2bf(f.w);
        }
    }
    *(ushort8*)(e + (size_t)r * KP + p8 * 8) = ve;
    *(ushort8*)(o + (size_t)r * KP + p8 * 8) = vo;
}

// Pass 2: split GEMM.
//  A-fragments: DIRECT per-lane 16B reg loads from e/o (wave-local layout,
//  row=l15, k=lhi*8) with 2-stage named-register prefetch (no LDS, no cvt).
//  B: 16 KB double-buffered LDS via global_load_lds, counted vmcnt(18) —
//  next-step A loads + B DMA stay in flight across both raw s_barriers.
//   out[r][2n]   = relu(0.5 E[r][n] + sum_k Bt1[n][k] * O[r][k])
//   out[r][2n+1] = relu(0.5 O[r][n] + sum_k Bt2[n][k] * E[r][k])
__global__ __launch_bounds__(256) void gemm_relu(
        const unsigned short* __restrict__ e,
        const unsigned short* __restrict__ o,
        const unsigned short* __restrict__ bt1,
        const unsigned short* __restrict__ bt2,
        float* __restrict__ out) {
    __shared__ unsigned short ldsB1[2][64 * 32];   // 2 x 4 KB
    __shared__ unsigned short ldsB2[2][64 * 32];   // 2 x 4 KB => 16 KB

    const int tid  = threadIdx.x;
    const int lane = tid & 63;
    const int wid  = tid >> 6;
    const int wr   = wid >> 1, wc = wid & 1;       // 2x2 wave grid
    const int l15  = lane & 15, lhi = lane >> 4;

    // bijective XCD swizzle (m204); 6 consecutive wgids share an A row-panel
    const int NX = 8;
    int orig = blockIdx.x;
    int q = NWG / NX, r = NWG % NX;                // 270, 6
    int xcd = orig % NX, local = orig / NX;
    int wgid = (xcd < r ? xcd * (q + 1) : r * (q + 1) + (xcd - r) * q) + local;
    const int bm  = (wgid / 6) * 128;
    const int bnp = (wgid % 6) * 64;               // pair-col base

    f32x4 acc_e[4][2], acc_o[4][2];
#pragma unroll
    for (int i = 0; i < 4; ++i)
#pragma unroll
        for (int j = 0; j < 2; ++j)
#pragma unroll
            for (int rr = 0; rr < 4; ++rr) { acc_e[i][j][rr] = 0.f; acc_o[i][j][rr] = 0.f; }

    // ---- B staging: 1 DMA per table per step, rotation-swizzled source ----
    const int brow = tid >> 2;      // 0..63 (pair-col row of Bt tile)
    const int bc   = tid & 3;       // 16B chunk id
    auto stageB = [&](int buf, int kt) {
        int gsrc = (bc - (brow >> 1)) & 3;
        size_t so = (size_t)(bnp + brow) * KP + kt * 32 + gsrc * 8;
        gload_lds16(bt1 + so, &ldsB1[buf][tid * 8]);
        gload_lds16(bt2 + so, &ldsB2[buf][tid * 8]);
    };

    // ---- A: direct per-lane fragment loads (natural MFMA layout) ----
    const unsigned short* eRow[4];
    const unsigned short* oRow[4];
#pragma unroll
    for (int mi = 0; mi < 4; ++mi) {
        size_t rb = (size_t)(bm + wr * 64 + mi * 16 + l15) * KP + lhi * 8;
        eRow[mi] = e + rb;
        oRow[mi] = o + rb;
    }
    auto loadA = [&](int kt, bf16x8 (&aE)[4], bf16x8 (&aO)[4]) {
#pragma unroll
        for (int mi = 0; mi < 4; ++mi) {
            aE[mi] = *(const bf16x8*)(eRow[mi] + kt * 32);
            aO[mi] = *(const bf16x8*)(oRow[mi] + kt * 32);
        }
    };

    auto compute = [&](int buf, const bf16x8 (&aE)[4], const bf16x8 (&aO)[4]) {
        bf16x8 b1[2], b2[2];
#pragma unroll
        for (int nf = 0; nf < 2; ++nf) {
            int row = wc * 32 + nf * 16 + l15;
            int c   = (lhi + (row >> 1)) & 3;
            b1[nf] = *(const bf16x8*)&ldsB1[buf][row * 32 + c * 8];
            b2[nf] = *(const bf16x8*)&ldsB2[buf][row * 32 + c * 8];
        }
        __builtin_amdgcn_s_setprio(1);
#pragma unroll
        for (int mi = 0; mi < 4; ++mi)
#pragma unroll
            for (int nf = 0; nf < 2; ++nf) {
                acc_e[mi][nf] = __builtin_amdgcn_mfma_f32_16x16x32_bf16(
                    aO[mi], b1[nf], acc_e[mi][nf], 0, 0, 0);
                acc_o[mi][nf] = __builtin_amdgcn_mfma_f32_16x16x32_bf16(
                    aE[mi], b2[nf], acc_o[mi][nf], 0, 0, 0);
            }
        __builtin_amdgcn_s_setprio(0);
    };

    // one step; all indices compile-time after unroll (rule 20)
    auto step = [&](int kt, int curbuf,
                    const bf16x8 (&aEc)[4], const bf16x8 (&aOc)[4],
                    bf16x8 (&aEn)[4], bf16x8 (&aOn)[4]) {
        if (kt + 1 < KT) {
            stageB(curbuf ^ 1, kt + 1);     // 2 DMA
            loadA(kt + 1, aEn, aOn);        // 8 reg loads (pinned below)
            // outstanding: B(kt)=2 oldest, A(kt)=8, B(kt+1)=2, A(kt+1)=8 = 20
            asm volatile("s_waitcnt vmcnt(18)" ::: "memory");  // B(kt) landed
        } else {
            // outstanding: B(kt)=2 oldest, A(kt)=8 = 10
            asm volatile("s_waitcnt vmcnt(8)" ::: "memory");   // B(kt) landed
        }
        __builtin_amdgcn_s_barrier();       // all waves' B(kt) visible
        __builtin_amdgcn_sched_barrier(0);
        compute(curbuf, aEc, aOc);          // compiler auto-waits A(kt) regs
        __builtin_amdgcn_s_barrier();       // readers done before next overwrite
        __builtin_amdgcn_sched_barrier(0);
    };

    // ---- prologue ----
    bf16x8 aEA[4], aOA[4], aEB[4], aOB[4];
    stageB(0, 0);
    loadA(0, aEA, aOA);

#pragma unroll
    for (int t2 = 0; t2 < KT / 2; ++t2) {
        step(2 * t2,     0, aEA, aOA, aEB, aOB);
        step(2 * t2 + 1, 1, aEB, aOB, aEA, aOA);
    }

    // ---- epilogue: +0.5*E/O identity (bf16 re-read), relu, float2 store ----
#pragma unroll
    for (int mi = 0; mi < 4; ++mi) {
#pragma unroll
        for (int nf = 0; nf < 2; ++nf) {
            int colp = bnp + wc * 32 + nf * 16 + l15;
            if (colp < PP) {
#pragma unroll
                for (int rr = 0; rr < 4; ++rr) {
                    int rowg = bm + wr * 64 + mi * 16 + lhi * 4 + rr;
                    size_t ib = (size_t)rowg * KP + colp;
                    float fe = bf2f(e[ib]);
                    float fo = bf2f(o[ib]);
                    float ye = 0.5f * fe + acc_e[mi][nf][rr];
                    float yo = 0.5f * fo + acc_o[mi][nf][rr];
                    float2 ov;
                    ov.x = ye > 0.f ? ye : 0.f;
                    ov.y = yo > 0.f ? yo : 0.f;
                    *(float2*)&out[(size_t)rowg * CC + 2 * colp] = ov;
                }
            }
        }
    }
}

extern "C" void kernel_launch(void* const* d_in, const int* in_sizes, int n_in,
                              void* d_out, int out_size, void* d_ws, size_t ws_size,
                              hipStream_t stream) {
    const float* x = (const float*)d_in[0];
    float* out = (float*)d_out;

    unsigned short* bt1 = (unsigned short*)d_ws;            // 384*384 bf16
    unsigned short* bt2 = bt1 + KP * KP;
    unsigned short* e   = bt2 + KP * KP;                    // 46208*384 bf16
    unsigned short* o   = e + (size_t)M_ROWS * KP;

    build_bt<<<(2 * KP * KP + 255) / 256, 256, 0, stream>>>(bt1, bt2);
    convert_deint<<<(M_ROWS * 48) / 256, 256, 0, stream>>>(x, e, o);
    gemm_relu<<<NWG, 256, 0, stream>>>(e, o, bt1, bt2, out);
}

// Round 13
// 132.391 us; speedup vs baseline: 1.2993x; 1.2993x over previous
//
#include <hip/hip_runtime.h>
#include <hip/hip_bf16.h>

#define CC 728
#define PP 364          // pairs (even/odd phase length)
#define KP 384          // padded pair-K: 48 chunks of 8 pairs
#define KT 12
#define ROWS 32         // rows per block
#define NWG 1444        // 46208 / 32

typedef __attribute__((ext_vector_type(8))) short bf16x8;
typedef __attribute__((ext_vector_type(8))) unsigned short ushort8;
typedef __attribute__((ext_vector_type(4))) float f32x4;

// round-to-nearest-even fp32 -> bf16 bits
__device__ __forceinline__ unsigned int f2bf(float f) {
    unsigned int u = __float_as_uint(f);
    unsigned int r = u + 0x7fffu + ((u >> 16) & 1u);
    return r >> 16;
}

__device__ __forceinline__ float bf2f(unsigned short v) {
    unsigned int u = ((unsigned int)v) << 16;
    return __uint_as_float(u);
}

// h[d] for odd d (validated closed form, rounds 1-12):
//   h[d] = s * cos(pi d/728) / (728 sin(pi d/728)),  s = +1 if (d>>1)&1 else -1
// Bt1[n][k] = h[2*((n-k-1) mod 364)+1]   (Ye = 0.5 E + Bt1 . O)
// Bt2[n][k] = h[2*((n-k)   mod 364)+1]   (Yo = 0.5 O + Bt2 . E)
// Both padded to [384][384] bf16, zero outside n<364 && k<364.
__global__ void build_bt(unsigned short* __restrict__ bt1,
                         unsigned short* __restrict__ bt2) {
    int idx = blockIdx.x * blockDim.x + threadIdx.x;
    if (idx >= 2 * KP * KP) return;
    int mat = idx / (KP * KP);
    int rem = idx % (KP * KP);
    int n = rem / KP, k = rem % KP;
    float v = 0.f;
    if (n < PP && k < PP) {
        int m = n - k - (mat == 0 ? 1 : 0);
        if (m < 0) m += PP;
        int d = 2 * m + 1;
        float t = (float)(3.14159265358979323846 * (double)d / (double)CC);
        float s = ((d >> 1) & 1) ? 1.f : -1.f;
        v = s * cosf(t) / ((float)CC * sinf(t));
    }
    (mat == 0 ? bt1 : bt2)[n * KP + k] = (unsigned short)f2bf(v);
}

// Fused convert + split GEMM, A-resident structure:
//  Phase 1: block converts its OWN 32x728 fp32 rows -> E/O bf16 [32][384]
//           in LDS (XOR-chunk swizzle). x read once. One barrier total.
//  Phase 2: 12 unrolled K-steps, ZERO barriers: A via ds_read from the
//           resident panel, B via direct per-lane 16B loads from L2-hot
//           bt tables (0.59 MB, resident per XCD). 8 free-running waves.
//  Epilogue: 0.5*identity from LDS, relu, guarded float2 stores.
//   out[r][2n]   = relu(0.5 E[r][n] + sum_k Bt1[n][k] * O[r][k])
//   out[r][2n+1] = relu(0.5 O[r][n] + sum_k Bt2[n][k] * E[r][k])
__global__ __launch_bounds__(512, 4) void fused_gemm_relu(
        const float* __restrict__ x,
        const unsigned short* __restrict__ bt1,
        const unsigned short* __restrict__ bt2,
        float* __restrict__ out) {
    __shared__ unsigned short ldsE[ROWS * KP];   // 24 KB
    __shared__ unsigned short ldsO[ROWS * KP];   // 24 KB

    const int tid  = threadIdx.x;
    const int lane = tid & 63;
    const int wid  = tid >> 6;                   // 0..7, wave's n-strip
    const int l15  = lane & 15, lhi = lane >> 4; // lhi in 0..3

    const int bm = blockIdx.x * ROWS;

    // ---- Phase 1: convert 32x728 fp32 -> E/O [32][384] bf16, swizzled ----
#pragma unroll
    for (int i = 0; i < 3; ++i) {
        int idx = i * 512 + tid;                 // 0..1535 = 32 rows * 48 chunks
        int row = idx / 48, p8 = idx % 48;
        int c0  = p8 * 16;                       // channel base (16 ch = 8 pairs)
        ushort8 ve, vo;
#pragma unroll
        for (int j = 0; j < 8; ++j) { ve[j] = 0; vo[j] = 0; }
        const float4* src = (const float4*)(x + (size_t)(bm + row) * CC + c0);
#pragma unroll
        for (int j = 0; j < 4; ++j) {
            if (c0 + 4 * j < CC) {
                float4 f = src[j];
                ve[2 * j]     = (unsigned short)f2bf(f.x);
                vo[2 * j]     = (unsigned short)f2bf(f.y);
                ve[2 * j + 1] = (unsigned short)f2bf(f.z);
                vo[2 * j + 1] = (unsigned short)f2bf(f.w);
            }
        }
        int pw = p8 ^ (row & 7);                 // XOR chunk swizzle
        *(ushort8*)&ldsE[row * KP + pw * 8] = ve;
        *(ushort8*)&ldsO[row * KP + pw * 8] = vo;
    }
    __syncthreads();    // the ONLY barrier; LDS read-only afterwards

    // ---- Phase 2: K-loop, no barriers ----
    f32x4 acc_e[2][3], acc_o[2][3];
#pragma unroll
    for (int i = 0; i < 2; ++i)
#pragma unroll
        for (int j = 0; j < 3; ++j)
#pragma unroll
            for (int rr = 0; rr < 4; ++rr) { acc_e[i][j][rr] = 0.f; acc_o[i][j][rr] = 0.f; }

    // per-lane B row pointers (n = wid*48 + nf*16 + l15), natural frag layout
    const unsigned short* b1p[3];
    const unsigned short* b2p[3];
#pragma unroll
    for (int nf = 0; nf < 3; ++nf) {
        size_t off = (size_t)(wid * 48 + nf * 16 + l15) * KP + lhi * 8;
        b1p[nf] = bt1 + off;
        b2p[nf] = bt2 + off;
    }

#pragma unroll
    for (int kt = 0; kt < KT; ++kt) {
        // B frags: direct 16B loads from L2-hot tables
        bf16x8 b1[3], b2[3];
#pragma unroll
        for (int nf = 0; nf < 3; ++nf) {
            b1[nf] = *(const bf16x8*)(b1p[nf] + kt * 32);
            b2[nf] = *(const bf16x8*)(b2p[nf] + kt * 32);
        }
        // A frags: ds_read from resident panel (swizzle-matched)
        bf16x8 aE[2], aO[2];
#pragma unroll
        for (int mi = 0; mi < 2; ++mi) {
            int row = mi * 16 + l15;
            int c   = (kt * 4 + lhi) ^ (row & 7);
            aE[mi] = *(const bf16x8*)&ldsE[row * KP + c * 8];
            aO[mi] = *(const bf16x8*)&ldsO[row * KP + c * 8];
        }
#pragma unroll
        for (int mi = 0; mi < 2; ++mi)
#pragma unroll
            for (int nf = 0; nf < 3; ++nf) {
                acc_e[mi][nf] = __builtin_amdgcn_mfma_f32_16x16x32_bf16(
                    aO[mi], b1[nf], acc_e[mi][nf], 0, 0, 0);
                acc_o[mi][nf] = __builtin_amdgcn_mfma_f32_16x16x32_bf16(
                    aE[mi], b2[nf], acc_o[mi][nf], 0, 0, 0);
            }
    }

    // ---- epilogue: +0.5*E/O from LDS, relu, interleaved float2 store ----
#pragma unroll
    for (int mi = 0; mi < 2; ++mi) {
#pragma unroll
        for (int nf = 0; nf < 3; ++nf) {
            int colp = wid * 48 + nf * 16 + l15;
            if (colp < PP) {
                int cch = colp >> 3;
#pragma unroll
                for (int rr = 0; rr < 4; ++rr) {
                    int lrow = mi * 16 + lhi * 4 + rr;
                    int cw   = cch ^ (lrow & 7);
                    float fe = bf2f(ldsE[lrow * KP + cw * 8 + (colp & 7)]);
                    float fo = bf2f(ldsO[lrow * KP + cw * 8 + (colp & 7)]);
                    float ye = 0.5f * fe + acc_e[mi][nf][rr];
                    float yo = 0.5f * fo + acc_o[mi][nf][rr];
                    float2 ov;
                    ov.x = ye > 0.f ? ye : 0.f;
                    ov.y = yo > 0.f ? yo : 0.f;
                    *(float2*)&out[(size_t)(bm + lrow) * CC + 2 * colp] = ov;
                }
            }
        }
    }
}

extern "C" void kernel_launch(void* const* d_in, const int* in_sizes, int n_in,
                              void* d_out, int out_size, void* d_ws, size_t ws_size,
                              hipStream_t stream) {
    const float* x = (const float*)d_in[0];
    float* out = (float*)d_out;

    unsigned short* bt1 = (unsigned short*)d_ws;            // 384*384 bf16
    unsigned short* bt2 = bt1 + KP * KP;                    // 384*384 bf16

    build_bt<<<(2 * KP * KP + 255) / 256, 256, 0, stream>>>(bt1, bt2);
    fused_gemm_relu<<<NWG, 512, 0, stream>>>(x, bt1, bt2, out);
}

// Round 14
// 120.321 us; speedup vs baseline: 1.4296x; 1.1003x over previous
//
#include <hip/hip_runtime.h>
#include <hip/hip_bf16.h>

#define CC 728
#define PP 364          // pairs (even/odd phase length)
#define KP 384          // padded pair-K: 12 * 32
#define KT 12
#define M_ROWS 46208    // 32*38*38 = 361 * 128
#define NWG 2166        // 361 m-tiles * 6 n-tiles (64 pairs each)

typedef __attribute__((ext_vector_type(8))) short bf16x8;
typedef __attribute__((ext_vector_type(8))) unsigned short ushort8;
typedef __attribute__((ext_vector_type(4))) float f32x4;

// round-to-nearest-even fp32 -> bf16 bits
__device__ __forceinline__ unsigned int f2bf(float f) {
    unsigned int u = __float_as_uint(f);
    unsigned int r = u + 0x7fffu + ((u >> 16) & 1u);
    return r >> 16;
}

__device__ __forceinline__ float bf2f(unsigned short v) {
    unsigned int u = ((unsigned int)v) << 16;
    return __uint_as_float(u);
}

__device__ __forceinline__ void gload_lds16(const void* g, void* l) {
    __builtin_amdgcn_global_load_lds(
        (const __attribute__((address_space(1))) void*)g,
        (__attribute__((address_space(3))) void*)l,
        16, 0, 0);
}

// h[d] for odd d (validated closed form, rounds 1-13):
//   h[d] = s * cos(pi d/728) / (728 sin(pi d/728)),  s = +1 if (d>>1)&1 else -1
// Bt1[n][k] = h[2*((n-k-1) mod 364)+1]   (Ye = 0.5 E + Bt1 . O)
// Bt2[n][k] = h[2*((n-k)   mod 364)+1]   (Yo = 0.5 O + Bt2 . E)
// Both padded to [384][384] bf16, zero outside n<364 && k<364.
__global__ void build_bt(unsigned short* __restrict__ bt1,
                         unsigned short* __restrict__ bt2) {
    int idx = blockIdx.x * blockDim.x + threadIdx.x;
    if (idx >= 2 * KP * KP) return;
    int mat = idx / (KP * KP);
    int rem = idx % (KP * KP);
    int n = rem / KP, k = rem % KP;
    float v = 0.f;
    if (n < PP && k < PP) {
        int m = n - k - (mat == 0 ? 1 : 0);
        if (m < 0) m += PP;
        int d = 2 * m + 1;
        float t = (float)(3.14159265358979323846 * (double)d / (double)CC);
        float s = ((d >> 1) & 1) ? 1.f : -1.f;
        v = s * cosf(t) / ((float)CC * sinf(t));
    }
    (mat == 0 ? bt1 : bt2)[n * KP + k] = (unsigned short)f2bf(v);
}

// Pass 1: x fp32 [46208][728] -> e,o bf16 [46208][384] (de-interleaved, padded)
__global__ void convert_deint(const float* __restrict__ x,
                              unsigned short* __restrict__ e,
                              unsigned short* __restrict__ o) {
    int id = blockIdx.x * blockDim.x + threadIdx.x;   // r*48 + p8
    if (id >= M_ROWS * 48) return;
    int r  = id / 48, p8 = id % 48;
    int c0 = p8 * 16;
    ushort8 ve, vo;
#pragma unroll
    for (int j = 0; j < 8; ++j) { ve[j] = 0; vo[j] = 0; }
    if (c0 < CC) {
        const float4* src = (const float4*)(x + (size_t)r * CC + c0);
#pragma unroll
        for (int j = 0; j < 4; ++j) {
            float4 f = (c0 + 4 * j < CC) ? src[j] : make_float4(0.f, 0.f, 0.f, 0.f);
            ve[2 * j]     = (unsigned short)f2bf(f.x);
            vo[2 * j]     = (unsigned short)f2bf(f.y);
            ve[2 * j + 1] = (unsigned short)f2bf(f.z);
            vo[2 * j + 1] = (unsigned short)f2bf(f.w);
        }
    }
    *(ushort8*)(e + (size_t)r * KP + p8 * 8) = ve;
    *(ushort8*)(o + (size_t)r * KP + p8 * 8) = vo;
}

// Pass 2: split GEMM, R10's proven pure-DMA staging + T3-min 2-phase schedule:
// STAGE(t+1) into the alternate buffer is issued BEFORE compute(t), so its
// latency hides under ds_read+MFMA; ONE __syncthreads per K-step (its vmcnt(0)
// waits loads that already had the compute phase to land). Double-buffered.
//   out[r][2n]   = relu(0.5 E[r][n] + sum_k Bt1[n][k] * O[r][k])
//   out[r][2n+1] = relu(0.5 O[r][n] + sum_k Bt2[n][k] * E[r][k])
__global__ __launch_bounds__(256) void gemm_relu(
        const unsigned short* __restrict__ e,
        const unsigned short* __restrict__ o,
        const unsigned short* __restrict__ bt1,
        const unsigned short* __restrict__ bt2,
        float* __restrict__ out) {
    __shared__ unsigned short ldsE[2][128 * 32];   // 2 x 8 KB
    __shared__ unsigned short ldsO[2][128 * 32];   // 2 x 8 KB
    __shared__ unsigned short ldsB1[2][64 * 32];   // 2 x 4 KB
    __shared__ unsigned short ldsB2[2][64 * 32];   // 2 x 4 KB  => 48 KB

    const int tid  = threadIdx.x;
    const int lane = tid & 63;
    const int wid  = tid >> 6;
    const int wr   = wid >> 1, wc = wid & 1;     // 2x2 wave grid
    const int l15  = lane & 15, lhi = lane >> 4;

    // bijective XCD swizzle (m204); 6 consecutive wgids share an A row-panel
    const int NX = 8;
    int orig = blockIdx.x;
    int q = NWG / NX, r = NWG % NX;              // 270, 6
    int xcd = orig % NX, local = orig / NX;
    int wgid = (xcd < r ? xcd * (q + 1) : r * (q + 1) + (xcd - r) * q) + local;
    const int bm  = (wgid / 6) * 128;
    const int bnp = (wgid % 6) * 64;             // pair-col base

    f32x4 acc_e[4][2], acc_o[4][2];
#pragma unroll
    for (int i = 0; i < 4; ++i)
#pragma unroll
        for (int j = 0; j < 2; ++j)
#pragma unroll
            for (int rr = 0; rr < 4; ++rr) { acc_e[i][j][rr] = 0.f; acc_o[i][j][rr] = 0.f; }

    const int rowA = tid >> 2;     // 0..63 staging row base
    const int cq   = tid & 3;      // 16B chunk id

    // ---- staging: 6 DMA / step (E 2, O 2, B1 1, B2 1), swizzled source ----
    auto stage = [&](int buf, int kt) {
        int k0 = kt * 32;
#pragma unroll
        for (int i = 0; i < 2; ++i) {
            int row  = i * 64 + rowA;
            int gsrc = (cq - (row >> 1)) & 3;
            size_t so = (size_t)(bm + row) * KP + k0 + gsrc * 8;
            gload_lds16(e + so, &ldsE[buf][(i * 256 + tid) * 8]);
            gload_lds16(o + so, &ldsO[buf][(i * 256 + tid) * 8]);
        }
        {
            int gsrc = (cq - (rowA >> 1)) & 3;
            size_t so = (size_t)(bnp + rowA) * KP + k0 + gsrc * 8;
            gload_lds16(bt1 + so, &ldsB1[buf][tid * 8]);
            gload_lds16(bt2 + so, &ldsB2[buf][tid * 8]);
        }
    };

    auto compute = [&](int buf) {
        bf16x8 aE[4], aO[4], b1[2], b2[2];
#pragma unroll
        for (int mi = 0; mi < 4; ++mi) {
            int row = wr * 64 + mi * 16 + l15;
            int c   = (lhi + (row >> 1)) & 3;
            aE[mi] = *(const bf16x8*)&ldsE[buf][row * 32 + c * 8];
            aO[mi] = *(const bf16x8*)&ldsO[buf][row * 32 + c * 8];
        }
#pragma unroll
        for (int nf = 0; nf < 2; ++nf) {
            int row = wc * 32 + nf * 16 + l15;
            int c   = (lhi + (row >> 1)) & 3;
            b1[nf] = *(const bf16x8*)&ldsB1[buf][row * 32 + c * 8];
            b2[nf] = *(const bf16x8*)&ldsB2[buf][row * 32 + c * 8];
        }
        __builtin_amdgcn_s_setprio(1);
#pragma unroll
        for (int mi = 0; mi < 4; ++mi)
#pragma unroll
            for (int nf = 0; nf < 2; ++nf) {
                acc_e[mi][nf] = __builtin_amdgcn_mfma_f32_16x16x32_bf16(
                    aO[mi], b1[nf], acc_e[mi][nf], 0, 0, 0);
                acc_o[mi][nf] = __builtin_amdgcn_mfma_f32_16x16x32_bf16(
                    aE[mi], b2[nf], acc_o[mi][nf], 0, 0, 0);
            }
        __builtin_amdgcn_s_setprio(0);
    };

    // ---- T3-min pipeline: stage-early, one barrier per step ----
    stage(0, 0);
    __syncthreads();
#pragma unroll
    for (int t2 = 0; t2 < KT / 2; ++t2) {
        // step 2*t2 (buf 0)
        if (2 * t2 + 1 < KT) stage(1, 2 * t2 + 1);
        compute(0);
        __syncthreads();   // waits stage(2t2+1) DMAs (flew during compute)
        // step 2*t2+1 (buf 1)
        if (2 * t2 + 2 < KT) stage(0, 2 * t2 + 2);
        compute(1);
        __syncthreads();
    }

    // ---- epilogue: +0.5*E/O identity (L3-hot re-read), relu, float2 store ----
#pragma unroll
    for (int mi = 0; mi < 4; ++mi) {
#pragma unroll
        for (int nf = 0; nf < 2; ++nf) {
            int colp = bnp + wc * 32 + nf * 16 + l15;
            if (colp < PP) {
#pragma unroll
                for (int rr = 0; rr < 4; ++rr) {
                    int rowg = bm + wr * 64 + mi * 16 + lhi * 4 + rr;
                    size_t ib = (size_t)rowg * KP + colp;
                    float fe = bf2f(e[ib]);
                    float fo = bf2f(o[ib]);
                    float ye = 0.5f * fe + acc_e[mi][nf][rr];
                    float yo = 0.5f * fo + acc_o[mi][nf][rr];
                    float2 ov;
                    ov.x = ye > 0.f ? ye : 0.f;
                    ov.y = yo > 0.f ? yo : 0.f;
                    *(float2*)&out[(size_t)rowg * CC + 2 * colp] = ov;
                }
            }
        }
    }
}

extern "C" void kernel_launch(void* const* d_in, const int* in_sizes, int n_in,
                              void* d_out, int out_size, void* d_ws, size_t ws_size,
                              hipStream_t stream) {
    const float* x = (const float*)d_in[0];
    float* out = (float*)d_out;

    unsigned short* bt1 = (unsigned short*)d_ws;            // 384*384 bf16
    unsigned short* bt2 = bt1 + KP * KP;
    unsigned short* e   = bt2 + KP * KP;                    // 46208*384 bf16
    unsigned short* o   = e + (size_t)M_ROWS * KP;

    build_bt<<<(2 * KP * KP + 255) / 256, 256, 0, stream>>>(bt1, bt2);
    convert_deint<<<(M_ROWS * 48) / 256, 256, 0, stream>>>(x, e, o);
    gemm_relu<<<NWG, 256, 0, stream>>>(e, o, bt1, bt2, out);
}

// Round 15
// 119.746 us; speedup vs baseline: 1.4365x; 1.0048x over previous
//
#include <hip/hip_runtime.h>
#include <hip/hip_bf16.h>

#define CC 728
#define PP 364          // pairs (even/odd phase length)
#define KP 384          // padded pair-K: 12 * 32
#define KT 12
#define M_ROWS 46208    // 32*38*38 = 361 * 128
#define NWG 2166        // 361 m-tiles * 6 n-tiles (64 pairs each)

typedef __attribute__((ext_vector_type(8))) short bf16x8;
typedef __attribute__((ext_vector_type(8))) unsigned short ushort8;
typedef __attribute__((ext_vector_type(4))) float f32x4;

// round-to-nearest-even fp32 -> bf16 bits
__device__ __forceinline__ unsigned int f2bf(float f) {
    unsigned int u = __float_as_uint(f);
    unsigned int r = u + 0x7fffu + ((u >> 16) & 1u);
    return r >> 16;
}

__device__ __forceinline__ float bf2f(unsigned short v) {
    unsigned int u = ((unsigned int)v) << 16;
    return __uint_as_float(u);
}

__device__ __forceinline__ void gload_lds16(const void* g, void* l) {
    __builtin_amdgcn_global_load_lds(
        (const __attribute__((address_space(1))) void*)g,
        (__attribute__((address_space(3))) void*)l,
        16, 0, 0);
}

// h[d] for odd d (validated closed form, rounds 1-14):
//   h[d] = s * cos(pi d/728) / (728 sin(pi d/728)),  s = +1 if (d>>1)&1 else -1
// Bt1[n][k] = h[2*((n-k-1) mod 364)+1]   (Ye = 0.5 E + Bt1 . O)
// Bt2[n][k] = h[2*((n-k)   mod 364)+1]   (Yo = 0.5 O + Bt2 . E)
// Both padded to [384][384] bf16, zero outside n<364 && k<364.
__global__ void build_bt(unsigned short* __restrict__ bt1,
                         unsigned short* __restrict__ bt2) {
    int idx = blockIdx.x * blockDim.x + threadIdx.x;
    if (idx >= 2 * KP * KP) return;
    int mat = idx / (KP * KP);
    int rem = idx % (KP * KP);
    int n = rem / KP, k = rem % KP;
    float v = 0.f;
    if (n < PP && k < PP) {
        int m = n - k - (mat == 0 ? 1 : 0);
        if (m < 0) m += PP;
        int d = 2 * m + 1;
        float t = (float)(3.14159265358979323846 * (double)d / (double)CC);
        float s = ((d >> 1) & 1) ? 1.f : -1.f;
        v = s * cosf(t) / ((float)CC * sinf(t));
    }
    (mat == 0 ? bt1 : bt2)[n * KP + k] = (unsigned short)f2bf(v);
}

// Pass 1: x fp32 [46208][728] -> e,o bf16 [46208][384] (de-interleaved, padded)
__global__ void convert_deint(const float* __restrict__ x,
                              unsigned short* __restrict__ e,
                              unsigned short* __restrict__ o) {
    int id = blockIdx.x * blockDim.x + threadIdx.x;   // r*48 + p8
    if (id >= M_ROWS * 48) return;
    int r  = id / 48, p8 = id % 48;
    int c0 = p8 * 16;
    ushort8 ve, vo;
#pragma unroll
    for (int j = 0; j < 8; ++j) { ve[j] = 0; vo[j] = 0; }
    if (c0 < CC) {
        const float4* src = (const float4*)(x + (size_t)r * CC + c0);
#pragma unroll
        for (int j = 0; j < 4; ++j) {
            float4 f = (c0 + 4 * j < CC) ? src[j] : make_float4(0.f, 0.f, 0.f, 0.f);
            ve[2 * j]     = (unsigned short)f2bf(f.x);
            vo[2 * j]     = (unsigned short)f2bf(f.y);
            ve[2 * j + 1] = (unsigned short)f2bf(f.z);
            vo[2 * j + 1] = (unsigned short)f2bf(f.w);
        }
    }
    *(ushort8*)(e + (size_t)r * KP + p8 * 8) = ve;
    *(ushort8*)(o + (size_t)r * KP + p8 * 8) = vo;
}

// Pass 2: split GEMM, R10's pure-DMA staging + TRUE counted-vmcnt pipeline:
// 3-deep LDS rotation, raw s_barriers (no drain), vmcnt(12) keeps stages
// t+1,t+2 (12 DMAs) in flight across barriers. Two barriers/step protect
// cross-wave tile completeness and the overwrite hazard; NO full drains.
//   out[r][2n]   = relu(0.5 E[r][n] + sum_k Bt1[n][k] * O[r][k])
//   out[r][2n+1] = relu(0.5 O[r][n] + sum_k Bt2[n][k] * E[r][k])
__global__ __launch_bounds__(256) void gemm_relu(
        const unsigned short* __restrict__ e,
        const unsigned short* __restrict__ o,
        const unsigned short* __restrict__ bt1,
        const unsigned short* __restrict__ bt2,
        float* __restrict__ out) {
    __shared__ unsigned short ldsE[3][128 * 32];   // 3 x 8 KB
    __shared__ unsigned short ldsO[3][128 * 32];   // 3 x 8 KB
    __shared__ unsigned short ldsB1[3][64 * 32];   // 3 x 4 KB
    __shared__ unsigned short ldsB2[3][64 * 32];   // 3 x 4 KB  => 72 KB

    const int tid  = threadIdx.x;
    const int lane = tid & 63;
    const int wid  = tid >> 6;
    const int wr   = wid >> 1, wc = wid & 1;     // 2x2 wave grid
    const int l15  = lane & 15, lhi = lane >> 4;

    // bijective XCD swizzle (m204); 6 consecutive wgids share an A row-panel
    const int NX = 8;
    int orig = blockIdx.x;
    int q = NWG / NX, r = NWG % NX;              // 270, 6
    int xcd = orig % NX, local = orig / NX;
    int wgid = (xcd < r ? xcd * (q + 1) : r * (q + 1) + (xcd - r) * q) + local;
    const int bm  = (wgid / 6) * 128;
    const int bnp = (wgid % 6) * 64;             // pair-col base

    f32x4 acc_e[4][2], acc_o[4][2];
#pragma unroll
    for (int i = 0; i < 4; ++i)
#pragma unroll
        for (int j = 0; j < 2; ++j)
#pragma unroll
            for (int rr = 0; rr < 4; ++rr) { acc_e[i][j][rr] = 0.f; acc_o[i][j][rr] = 0.f; }

    const int rowA = tid >> 2;     // 0..63 staging row base
    const int cq   = tid & 3;      // 16B chunk id

    // ---- staging: 6 DMA / step (E 2, O 2, B1 1, B2 1), swizzled source ----
    auto stage = [&](int buf, int kt) {
        int k0 = kt * 32;
#pragma unroll
        for (int i = 0; i < 2; ++i) {
            int row  = i * 64 + rowA;
            int gsrc = (cq - (row >> 1)) & 3;
            size_t so = (size_t)(bm + row) * KP + k0 + gsrc * 8;
            gload_lds16(e + so, &ldsE[buf][(i * 256 + tid) * 8]);
            gload_lds16(o + so, &ldsO[buf][(i * 256 + tid) * 8]);
        }
        {
            int gsrc = (cq - (rowA >> 1)) & 3;
            size_t so = (size_t)(bnp + rowA) * KP + k0 + gsrc * 8;
            gload_lds16(bt1 + so, &ldsB1[buf][tid * 8]);
            gload_lds16(bt2 + so, &ldsB2[buf][tid * 8]);
        }
    };

    auto compute = [&](int buf) {
        bf16x8 aE[4], aO[4], b1[2], b2[2];
#pragma unroll
        for (int mi = 0; mi < 4; ++mi) {
            int row = wr * 64 + mi * 16 + l15;
            int c   = (lhi + (row >> 1)) & 3;
            aE[mi] = *(const bf16x8*)&ldsE[buf][row * 32 + c * 8];
            aO[mi] = *(const bf16x8*)&ldsO[buf][row * 32 + c * 8];
        }
#pragma unroll
        for (int nf = 0; nf < 2; ++nf) {
            int row = wc * 32 + nf * 16 + l15;
            int c   = (lhi + (row >> 1)) & 3;
            b1[nf] = *(const bf16x8*)&ldsB1[buf][row * 32 + c * 8];
            b2[nf] = *(const bf16x8*)&ldsB2[buf][row * 32 + c * 8];
        }
        __builtin_amdgcn_s_setprio(1);
#pragma unroll
        for (int mi = 0; mi < 4; ++mi)
#pragma unroll
            for (int nf = 0; nf < 2; ++nf) {
                acc_e[mi][nf] = __builtin_amdgcn_mfma_f32_16x16x32_bf16(
                    aO[mi], b1[nf], acc_e[mi][nf], 0, 0, 0);
                acc_o[mi][nf] = __builtin_amdgcn_mfma_f32_16x16x32_bf16(
                    aE[mi], b2[nf], acc_o[mi][nf], 0, 0, 0);
            }
        __builtin_amdgcn_s_setprio(0);
    };

    // ---- prologue: 3 stages in flight (18 DMA) ----
    stage(0, 0);
    stage(1, 1);
    stage(2, 2);

#pragma unroll
    for (int t = 0; t < KT; ++t) {
        // drain ONLY stage(t); keep stage(t+1), stage(t+2) (12 DMA) flying
        if (t < KT - 2)       asm volatile("s_waitcnt vmcnt(12)" ::: "memory");
        else if (t == KT - 2) asm volatile("s_waitcnt vmcnt(6)"  ::: "memory");
        else                  asm volatile("s_waitcnt vmcnt(0)"  ::: "memory");
        __builtin_amdgcn_s_barrier();          // all waves' stage(t) complete
        __builtin_amdgcn_sched_barrier(0);

        compute(t % 3);

        __builtin_amdgcn_s_barrier();          // all waves done reading buf t%3
        __builtin_amdgcn_sched_barrier(0);
        if (t + 3 < KT) stage(t % 3, t + 3);   // refill vacated buffer
    }

    // ---- epilogue: +0.5*E/O identity (L3-hot re-read), relu, float2 store ----
#pragma unroll
    for (int mi = 0; mi < 4; ++mi) {
#pragma unroll
        for (int nf = 0; nf < 2; ++nf) {
            int colp = bnp + wc * 32 + nf * 16 + l15;
            if (colp < PP) {
#pragma unroll
                for (int rr = 0; rr < 4; ++rr) {
                    int rowg = bm + wr * 64 + mi * 16 + lhi * 4 + rr;
                    size_t ib = (size_t)rowg * KP + colp;
                    float fe = bf2f(e[ib]);
                    float fo = bf2f(o[ib]);
                    float ye = 0.5f * fe + acc_e[mi][nf][rr];
                    float yo = 0.5f * fo + acc_o[mi][nf][rr];
                    float2 ov;
                    ov.x = ye > 0.f ? ye : 0.f;
                    ov.y = yo > 0.f ? yo : 0.f;
                    *(float2*)&out[(size_t)rowg * CC + 2 * colp] = ov;
                }
            }
        }
    }
}

extern "C" void kernel_launch(void* const* d_in, const int* in_sizes, int n_in,
                              void* d_out, int out_size, void* d_ws, size_t ws_size,
                              hipStream_t stream) {
    const float* x = (const float*)d_in[0];
    float* out = (float*)d_out;

    unsigned short* bt1 = (unsigned short*)d_ws;            // 384*384 bf16
    unsigned short* bt2 = bt1 + KP * KP;
    unsigned short* e   = bt2 + KP * KP;                    // 46208*384 bf16
    unsigned short* o   = e + (size_t)M_ROWS * KP;

    build_bt<<<(2 * KP * KP + 255) / 256, 256, 0, stream>>>(bt1, bt2);
    convert_deint<<<(M_ROWS * 48) / 256, 256, 0, stream>>>(x, e, o);
    gemm_relu<<<NWG, 256, 0, stream>>>(e, o, bt1, bt2, out);
}